// Round 6
// baseline (410.349 us; speedup 1.0000x reference)
//
#include <hip/hip_runtime.h>

typedef _Float16 f16;
typedef f16 f16x2 __attribute__((ext_vector_type(2)));
typedef f16 f16x4 __attribute__((ext_vector_type(4)));
typedef f16 f16x8 __attribute__((ext_vector_type(8)));
typedef float f32x4 __attribute__((ext_vector_type(4)));

union v8split { f16x8 v8; f16x2 v2[4]; };

#define QKV_OFF 65536                  // after buf0 (32KB) + buf1 (32KB)
#define SMEM_TOTAL 163840              // + qkv 64*1536 = 96KB  -> 160KB exactly

// d_ws layout
#define WQH_OFF 0
#define WPH_OFF (768 * 256 * 2)
#define XW_OFF  (WPH_OFF + 256 * 256 * 2)
#define O2_OFF  (XW_OFF + (size_t)2048 * 16384 * 2)

// fp32 -> fp16 weight conversion (w_qkv 768x256, w_proj 256x256)
__global__ __launch_bounds__(256) void cvt_weights_k(
    const float* __restrict__ wq, const float* __restrict__ wp,
    f16* __restrict__ wq_h, f16* __restrict__ wp_h) {
  int idx = blockIdx.x * 256 + threadIdx.x;
  if (idx < 768 * 256) wq_h[idx] = (f16)wq[idx];
  else wp_h[idx - 768 * 256] = (f16)wp[idx - 768 * 256];
}

// XOR-swizzled addr into a 64x512B tile (xw / out2).
__device__ __forceinline__ char* xwp(char* s, int row, int colbyte) {
  return s + row * 512 + (colbyte ^ (((row ^ (row >> 3)) & 7) << 4));
}
// qkv tile [64 t][768 f], row stride 1536B, swizzled for b128 reads.
__device__ __forceinline__ char* qvp(char* s, int t, int fbyte) {
  return s + QKV_OFF + t * 1536 + (fbyte ^ ((t & 7) << 4));
}

// swap with the adjacent lane (lane ^ 1) via quad_perm [1,0,3,2]
__device__ __forceinline__ float qswapf(float v) {
  int x = __builtin_bit_cast(int, v);
  x = __builtin_amdgcn_update_dpp(0, x, 0xB1, 0xf, 0xf, true);
  return __builtin_bit_cast(float, x);
}

#if __has_builtin(__builtin_amdgcn_fdot2)
__device__ __forceinline__ float fdot2f(f16x2 a, f16x2 b, float c) {
  return __builtin_amdgcn_fdot2(a, b, c, false);
}
#else
__device__ __forceinline__ float fdot2f(f16x2 a, f16x2 b, float c) {
  return c + (float)a[0] * (float)b[0] + (float)a[1] * (float)b[1];
}
#endif

// ---- K1: gather/transpose x (fp32 strided, full-line reads) -> xw_all
// (fp16, per-window contiguous, PRE-SWIZZLED to match xwp).
__global__ __launch_bounds__(256) void gather_k(const float* __restrict__ x,
                                                f16* __restrict__ xw_all) {
  const int g = blockIdx.x >> 4, cb = blockIdx.x & 15;
  const int b = g >> 6, iw = (g >> 3) & 7, jw = g & 7;
  const int tid = threadIdx.x;
  const int c = cb * 16 + (tid >> 4), a = (tid >> 2) & 3, bb = tid & 3;
  const float* src = x + (size_t)b * 8388608 + (size_t)c * 32768 +
                     (iw * 4 + a) * 1024 + (jw * 4 + bb) * 32;
  const int t = c >> 2;
  const int c2b = (c & 3) * 128 + a * 32 + bb * 8;
  const int byt = t * 512 + (c2b ^ (((t ^ (t >> 3)) & 7) << 4));
  char* wbase = (char*)(xw_all + (size_t)(g << 3) * 16384) + byt;
#pragma unroll
  for (int kw = 0; kw < 8; ++kw) {
    float4 v = *(const float4*)(src + kw * 4);
    f16x4 h;
    h[0] = (f16)v.x; h[1] = (f16)v.y; h[2] = (f16)v.z; h[3] = (f16)v.w;
    *(f16x4*)(wbase + kw * 32768) = h;
  }
}

// ---- K3: scatter o2T (fp16 contiguous) -> out (fp32, full-line writes).
__global__ __launch_bounds__(256) void scatter_k(const f16* __restrict__ o2T,
                                                 float* __restrict__ out) {
  const int g = blockIdx.x >> 4, cb = blockIdx.x & 15;
  const int b = g >> 6, iw = (g >> 3) & 7, jw = g & 7;
  const int tid = threadIdx.x;
  const int c3 = cb * 16 + (tid >> 4), a = (tid >> 2) & 3, bb = tid & 3;
  const f16* rbase = o2T + (size_t)(g << 3) * 16384 + c3 * 64 + a * 16 + bb * 4;
  float* dst = out + (size_t)b * 8388608 + (size_t)c3 * 32768 +
               (iw * 4 + a) * 1024 + (jw * 4 + bb) * 32;
#pragma unroll
  for (int kw = 0; kw < 8; ++kw) {
    f16x4 h = *(const f16x4*)(rbase + kw * 16384);
    float4 v;
    v.x = (float)h[0]; v.y = (float)h[1]; v.z = (float)h[2]; v.w = (float)h[3];
    *(float4*)(dst + kw * 4) = v;
  }
}

// ---- K2 window body ----
__device__ __forceinline__ void win_body(
    char* smem, char* bufX, char* bufY, const f16* xw_all, const f16* wq_h,
    const f16* wp_h, f16* o2T, int wi, bool pf, int wv, int lane, int lcol,
    int lq) {
  // GEMM1: qkv[64t x 768f] = (W @ xw^T)^T via mfma(A=W, B=xw): D col=token.
  {
    f32x4 acc[6][4] = {};
    const int fs = wv * 96;
#pragma unroll
    for (int kt = 0; kt < 8; ++kt) {
      f16x8 bf[4];
#pragma unroll
      for (int nt = 0; nt < 4; ++nt)
        bf[nt] = *(const f16x8*)xwp(bufX, nt * 16 + lcol, kt * 64 + lq * 16);
#pragma unroll
      for (int ms = 0; ms < 6; ++ms) {
        f16x8 af = *(const f16x8*)(wq_h + (fs + ms * 16 + lcol) * 256 + kt * 32 + lq * 8);
#pragma unroll
        for (int nt = 0; nt < 4; ++nt)
          acc[ms][nt] = __builtin_amdgcn_mfma_f32_16x16x32_f16(af, bf[nt], acc[ms][nt], 0, 0, 0);
      }
    }
    // D: col(lane&15)=token, row(lq*4+r)=feature -> f16x4 to qkv[t][f].
#pragma unroll
    for (int ms = 0; ms < 6; ++ms)
#pragma unroll
      for (int nt = 0; nt < 4; ++nt) {
        f16x4 hv;
        hv[0] = (f16)acc[ms][nt][0]; hv[1] = (f16)acc[ms][nt][1];
        hv[2] = (f16)acc[ms][nt][2]; hv[3] = (f16)acc[ms][nt][3];
        *(f16x4*)qvp(smem, nt * 16 + lcol, (fs + ms * 16 + lq * 4) * 2) = hv;
      }
  }
  __syncthreads();  // bar1: qkv visible; all waves done with bufX/bufY GEMMs

  if (pf) {  // prefetch next window's xw into bufY (drained by bar2)
    const char* g = (const char*)(xw_all + (size_t)(wi + 1) * 16384) + wv * 4096 + lane * 16;
#pragma unroll
    for (int i = 0; i < 4; ++i)
      __builtin_amdgcn_global_load_lds(
          (const __attribute__((address_space(1))) void*)(g + i * 1024),
          (__attribute__((address_space(3))) void*)(bufY + wv * 4096 + i * 1024), 16, 0, 0);
  }

  // Attention: wave owns 8 tokens. lane = (tt<<3 | h<<1 | dh).
  // Each lane: S[h][g] partial over its 32-d half (K streamed g-wise from
  // LDS, 4 h-lanes broadcast-read the same address), one quad_perm swap to
  // merge halves, per-lane softmax, then V streamed g-wise with fp32 O accum.
  {
    const int tt = lane >> 3, h = (lane >> 1) & 3, dh = lane & 1;
    const int t = wv * 8 + tt;
    const int db = dh * 64;  // byte offset of this lane's d-half (32 halfs)

    f16x2 q2[16];
#pragma unroll
    for (int j = 0; j < 4; ++j) {
      v8split u;
      u.v8 = *(const f16x8*)qvp(smem, t, h * 128 + db + j * 16);
      q2[j * 4 + 0] = u.v2[0]; q2[j * 4 + 1] = u.v2[1];
      q2[j * 4 + 2] = u.v2[2]; q2[j * 4 + 3] = u.v2[3];
    }
    float s[4];
#pragma unroll
    for (int g = 0; g < 4; ++g) {
      float a = 0.f;
#pragma unroll
      for (int j = 0; j < 4; ++j) {
        v8split u;
        u.v8 = *(const f16x8*)qvp(smem, t, 512 + g * 128 + db + j * 16);
        a = fdot2f(q2[j * 4 + 0], u.v2[0], a);
        a = fdot2f(q2[j * 4 + 1], u.v2[1], a);
        a = fdot2f(q2[j * 4 + 2], u.v2[2], a);
        a = fdot2f(q2[j * 4 + 3], u.v2[3], a);
      }
      s[g] = a;
    }
    // merge the two d-halves (lane ^ 1), both lanes end with the full dot
#pragma unroll
    for (int g = 0; g < 4; ++g) s[g] += qswapf(s[g]);

    float mx = -1e30f;
#pragma unroll
    for (int g = 0; g < 4; ++g) {
      float v = fminf(fmaxf(s[g] * 0.125f, -10.f), 10.f);  // clip BEFORE softmax
      s[g] = v; mx = fmaxf(mx, v);
    }
    float sum = 0.f;
#pragma unroll
    for (int g = 0; g < 4; ++g) { s[g] = __expf(s[g] - mx); sum += s[g]; }
    float inv = 1.f / sum;
#pragma unroll
    for (int g = 0; g < 4; ++g) s[g] *= inv;

    // O[t][h][d-half] in fp32 (32 values), V streamed g-wise (broadcast reads)
    float o[32] = {};
#pragma unroll
    for (int g = 0; g < 4; ++g) {
      float p = s[g];
#pragma unroll
      for (int j = 0; j < 4; ++j) {
        v8split u;
        u.v8 = *(const f16x8*)qvp(smem, t, 1024 + g * 128 + db + j * 16);
#pragma unroll
        for (int i = 0; i < 4; ++i) {
          o[j * 8 + 2 * i]     += p * (float)u.v2[i][0];
          o[j * 8 + 2 * i + 1] += p * (float)u.v2[i][1];
        }
      }
    }
    // out2 row = h*16 + t/4, colbyte = (t&3)*128 + dh*64 + j*16. Reuse bufX.
    const int row = h * 16 + (t >> 2);
    const int cb0 = (t & 3) * 128 + db;
#pragma unroll
    for (int j = 0; j < 4; ++j) {
      f16x8 ov;
      ov[0] = (f16)o[j * 8 + 0]; ov[1] = (f16)o[j * 8 + 1];
      ov[2] = (f16)o[j * 8 + 2]; ov[3] = (f16)o[j * 8 + 3];
      ov[4] = (f16)o[j * 8 + 4]; ov[5] = (f16)o[j * 8 + 5];
      ov[6] = (f16)o[j * 8 + 6]; ov[7] = (f16)o[j * 8 + 7];
      *(f16x8*)xwp(bufX, row, cb0 + j * 16) = ov;
    }
  }
  __syncthreads();  // bar2: out2 visible; prefetch drained

  // GEMM2: final[64 x 256] = out2 @ w_proj^T; D col=c3 -> o2T[c3][t].
  {
    f32x4 acc2[4][2] = {};
#pragma unroll
    for (int kt = 0; kt < 8; ++kt) {
      f16x8 afr[4];
#pragma unroll
      for (int mt = 0; mt < 4; ++mt)
        afr[mt] = *(const f16x8*)xwp(bufX, mt * 16 + lcol, kt * 64 + lq * 16);
#pragma unroll
      for (int nt = 0; nt < 2; ++nt) {
        f16x8 bfr = *(const f16x8*)(wp_h + (wv * 32 + nt * 16 + lcol) * 256 + kt * 32 + lq * 8);
#pragma unroll
        for (int mt = 0; mt < 4; ++mt)
          acc2[mt][nt] = __builtin_amdgcn_mfma_f32_16x16x32_f16(afr[mt], bfr, acc2[mt][nt], 0, 0, 0);
      }
    }
    f16* ob = o2T + (size_t)wi * 16384;
#pragma unroll
    for (int mt = 0; mt < 4; ++mt)
#pragma unroll
      for (int nt = 0; nt < 2; ++nt) {
        int c3 = wv * 32 + nt * 16 + lcol;
        f16x4 hv;
        hv[0] = (f16)acc2[mt][nt][0]; hv[1] = (f16)acc2[mt][nt][1];
        hv[2] = (f16)acc2[mt][nt][2]; hv[3] = (f16)acc2[mt][nt][3];
        *(f16x4*)(ob + c3 * 64 + mt * 16 + lq * 4) = hv;
      }
  }
  // no trailing barrier: next GEMM1 touches qkv (safe after bar2) and bufY.
}

// ---- K2: persistent block = 8 windows, double-buffered xw prefetch ----
// __launch_bounds__(512, 2): 2 waves/SIMD is the LDS-bound occupancy (160KB
// -> 1 block/CU); this raises the VGPR cap to 256 and eliminates the scratch
// spills that dominated rounds 4-5 (FETCH 547MB / WRITE 263MB of spill traffic
// at the default 128-VGPR target).
__global__ __launch_bounds__(512, 2) void win_attn_k(
    const f16* __restrict__ xw_all, const f16* __restrict__ wq_h,
    const f16* __restrict__ wp_h, f16* __restrict__ o2T) {
  extern __shared__ char smem[];
  const int tid = threadIdx.x, wv = tid >> 6, lane = tid & 63;
  const int lcol = lane & 15, lq = lane >> 4;
  const int base = blockIdx.x * 8;
  char* buf0 = smem;
  char* buf1 = smem + 32768;
  {
    const char* g = (const char*)(xw_all + (size_t)base * 16384) + wv * 4096 + lane * 16;
#pragma unroll
    for (int i = 0; i < 4; ++i)
      __builtin_amdgcn_global_load_lds(
          (const __attribute__((address_space(1))) void*)(g + i * 1024),
          (__attribute__((address_space(3))) void*)(buf0 + wv * 4096 + i * 1024), 16, 0, 0);
  }
  __syncthreads();
#pragma unroll 1
  for (int jj = 0; jj < 4; ++jj) {
    win_body(smem, buf0, buf1, xw_all, wq_h, wp_h, o2T, base + 2 * jj, true, wv, lane, lcol, lq);
    win_body(smem, buf1, buf0, xw_all, wq_h, wp_h, o2T, base + 2 * jj + 1, jj != 3, wv, lane, lcol, lq);
  }
}

extern "C" void kernel_launch(void* const* d_in, const int* in_sizes, int n_in,
                              void* d_out, int out_size, void* d_ws, size_t ws_size,
                              hipStream_t stream) {
  const float* x = (const float*)d_in[0];
  const float* wq = (const float*)d_in[1];
  const float* wp = (const float*)d_in[2];
  float* out = (float*)d_out;
  char* ws = (char*)d_ws;
  f16* wq_h = (f16*)(ws + WQH_OFF);
  f16* wp_h = (f16*)(ws + WPH_OFF);
  f16* xw_all = (f16*)(ws + XW_OFF);
  f16* o2T = (f16*)(ws + O2_OFF);

  (void)hipFuncSetAttribute((const void*)win_attn_k,
                            hipFuncAttributeMaxDynamicSharedMemorySize, SMEM_TOTAL);

  cvt_weights_k<<<1024, 256, 0, stream>>>(wq, wp, wq_h, wp_h);
  gather_k<<<4096, 256, 0, stream>>>(x, xw_all);
  win_attn_k<<<256, 512, SMEM_TOTAL, stream>>>(xw_all, wq_h, wp_h, o2T);
  scatter_k<<<4096, 256, 0, stream>>>(o2T, out);
}

// Round 7
// 321.012 us; speedup vs baseline: 1.2783x; 1.2783x over previous
//
#include <hip/hip_runtime.h>

typedef _Float16 f16;
typedef f16 f16x2 __attribute__((ext_vector_type(2)));
typedef f16 f16x4 __attribute__((ext_vector_type(4)));
typedef f16 f16x8 __attribute__((ext_vector_type(8)));
typedef float f32x4 __attribute__((ext_vector_type(4)));

union v8split { f16x8 v8; f16x2 v2[4]; };

#define QKV_OFF 65536                  // after buf0 (32KB) + buf1 (32KB)
#define SMEM_TOTAL 163840              // + qkv 64*1536 = 96KB  -> 160KB exactly

// d_ws layout
#define WQH_OFF 0
#define WPH_OFF (768 * 256 * 2)
#define XW_OFF  (WPH_OFF + 256 * 256 * 2)
#define O2_OFF  (XW_OFF + (size_t)2048 * 16384 * 2)

// fp32 -> fp16 weight conversion (w_qkv 768x256, w_proj 256x256)
__global__ __launch_bounds__(256) void cvt_weights_k(
    const float* __restrict__ wq, const float* __restrict__ wp,
    f16* __restrict__ wq_h, f16* __restrict__ wp_h) {
  int idx = blockIdx.x * 256 + threadIdx.x;
  if (idx < 768 * 256) wq_h[idx] = (f16)wq[idx];
  else wp_h[idx - 768 * 256] = (f16)wp[idx - 768 * 256];
}

// XOR-swizzled addr into a 64x512B tile (xw / out2).
__device__ __forceinline__ char* xwp(char* s, int row, int colbyte) {
  return s + row * 512 + (colbyte ^ (((row ^ (row >> 3)) & 7) << 4));
}
// qkv tile [64 t][768 f], row stride 1536B, swizzled for b128 reads.
__device__ __forceinline__ char* qvp(char* s, int t, int fbyte) {
  return s + QKV_OFF + t * 1536 + (fbyte ^ ((t & 7) << 4));
}

// swap with the adjacent lane (lane ^ 1) via quad_perm [1,0,3,2]
__device__ __forceinline__ float qswapf(float v) {
  int x = __builtin_bit_cast(int, v);
  x = __builtin_amdgcn_update_dpp(0, x, 0xB1, 0xf, 0xf, true);
  return __builtin_bit_cast(float, x);
}

#if __has_builtin(__builtin_amdgcn_fdot2)
__device__ __forceinline__ float fdot2f(f16x2 a, f16x2 b, float c) {
  return __builtin_amdgcn_fdot2(a, b, c, false);
}
#else
__device__ __forceinline__ float fdot2f(f16x2 a, f16x2 b, float c) {
  return c + (float)a[0] * (float)b[0] + (float)a[1] * (float)b[1];
}
#endif

// ---- K1: gather/transpose x (fp32 strided, full-line reads) -> xw_all
// (fp16, per-window contiguous, PRE-SWIZZLED to match xwp).
__global__ __launch_bounds__(256) void gather_k(const float* __restrict__ x,
                                                f16* __restrict__ xw_all) {
  const int g = blockIdx.x >> 4, cb = blockIdx.x & 15;
  const int b = g >> 6, iw = (g >> 3) & 7, jw = g & 7;
  const int tid = threadIdx.x;
  const int c = cb * 16 + (tid >> 4), a = (tid >> 2) & 3, bb = tid & 3;
  const float* src = x + (size_t)b * 8388608 + (size_t)c * 32768 +
                     (iw * 4 + a) * 1024 + (jw * 4 + bb) * 32;
  const int t = c >> 2;
  const int c2b = (c & 3) * 128 + a * 32 + bb * 8;
  const int byt = t * 512 + (c2b ^ (((t ^ (t >> 3)) & 7) << 4));
  char* wbase = (char*)(xw_all + (size_t)(g << 3) * 16384) + byt;
#pragma unroll
  for (int kw = 0; kw < 8; ++kw) {
    float4 v = *(const float4*)(src + kw * 4);
    f16x4 h;
    h[0] = (f16)v.x; h[1] = (f16)v.y; h[2] = (f16)v.z; h[3] = (f16)v.w;
    *(f16x4*)(wbase + kw * 32768) = h;
  }
}

// ---- K3: scatter o2T (fp16 contiguous) -> out (fp32, full-line writes).
__global__ __launch_bounds__(256) void scatter_k(const f16* __restrict__ o2T,
                                                 float* __restrict__ out) {
  const int g = blockIdx.x >> 4, cb = blockIdx.x & 15;
  const int b = g >> 6, iw = (g >> 3) & 7, jw = g & 7;
  const int tid = threadIdx.x;
  const int c3 = cb * 16 + (tid >> 4), a = (tid >> 2) & 3, bb = tid & 3;
  const f16* rbase = o2T + (size_t)(g << 3) * 16384 + c3 * 64 + a * 16 + bb * 4;
  float* dst = out + (size_t)b * 8388608 + (size_t)c3 * 32768 +
               (iw * 4 + a) * 1024 + (jw * 4 + bb) * 32;
#pragma unroll
  for (int kw = 0; kw < 8; ++kw) {
    f16x4 h = *(const f16x4*)(rbase + kw * 16384);
    float4 v;
    v.x = (float)h[0]; v.y = (float)h[1]; v.z = (float)h[2]; v.w = (float)h[3];
    *(float4*)(dst + kw * 4) = v;
  }
}

// ---- K2 window body ----
__device__ __forceinline__ void win_body(
    char* smem, char* bufX, char* bufY, const f16* xw_all, const f16* wq_h,
    const f16* wp_h, f16* o2T, int wi, bool pf, int wv, int lane, int lcol,
    int lq) {
  // GEMM1: qkv[64t x 768f] = (W @ xw^T)^T via mfma(A=W, B=xw): D col=token.
  // Split over ms into 2 passes of acc[3][4] (48 acc-VGPRs) so peak live
  // registers stay well under 128: rounds 4-6's acc[6][4]=96 spilled to
  // scratch (FETCH 541MB vs 35MB legit) and dominated runtime.
#pragma unroll 1
  for (int half = 0; half < 2; ++half) {
    f32x4 acc[3][4] = {};
    const int fs = wv * 96 + half * 48;
#pragma unroll
    for (int kt = 0; kt < 8; ++kt) {
      f16x8 bf[4];
#pragma unroll
      for (int nt = 0; nt < 4; ++nt)
        bf[nt] = *(const f16x8*)xwp(bufX, nt * 16 + lcol, kt * 64 + lq * 16);
#pragma unroll
      for (int ms = 0; ms < 3; ++ms) {
        f16x8 af = *(const f16x8*)(wq_h + (fs + ms * 16 + lcol) * 256 + kt * 32 + lq * 8);
#pragma unroll
        for (int nt = 0; nt < 4; ++nt)
          acc[ms][nt] = __builtin_amdgcn_mfma_f32_16x16x32_f16(af, bf[nt], acc[ms][nt], 0, 0, 0);
      }
    }
    // D: col(lane&15)=token, row(lq*4+r)=feature -> f16x4 to qkv[t][f].
#pragma unroll
    for (int ms = 0; ms < 3; ++ms)
#pragma unroll
      for (int nt = 0; nt < 4; ++nt) {
        f16x4 hv;
        hv[0] = (f16)acc[ms][nt][0]; hv[1] = (f16)acc[ms][nt][1];
        hv[2] = (f16)acc[ms][nt][2]; hv[3] = (f16)acc[ms][nt][3];
        *(f16x4*)qvp(smem, nt * 16 + lcol, (fs + ms * 16 + lq * 4) * 2) = hv;
      }
  }
  __syncthreads();  // bar1: qkv visible; all waves done with bufX/bufY GEMMs

  if (pf) {  // prefetch next window's xw into bufY (drained by bar2)
    const char* g = (const char*)(xw_all + (size_t)(wi + 1) * 16384) + wv * 4096 + lane * 16;
#pragma unroll
    for (int i = 0; i < 4; ++i)
      __builtin_amdgcn_global_load_lds(
          (const __attribute__((address_space(1))) void*)(g + i * 1024),
          (__attribute__((address_space(3))) void*)(bufY + wv * 4096 + i * 1024), 16, 0, 0);
  }

  // Attention: wave owns 8 tokens. lane = (tt<<3 | h<<1 | dh).
  // Each lane: S[h][g] partial over its 32-d half (K streamed g-wise from
  // LDS, 4 h-lanes broadcast-read the same address), one quad_perm swap to
  // merge halves, per-lane softmax, then V streamed g-wise with fp32 O accum.
  {
    const int tt = lane >> 3, h = (lane >> 1) & 3, dh = lane & 1;
    const int t = wv * 8 + tt;
    const int db = dh * 64;  // byte offset of this lane's d-half (32 halfs)

    f16x2 q2[16];
#pragma unroll
    for (int j = 0; j < 4; ++j) {
      v8split u;
      u.v8 = *(const f16x8*)qvp(smem, t, h * 128 + db + j * 16);
      q2[j * 4 + 0] = u.v2[0]; q2[j * 4 + 1] = u.v2[1];
      q2[j * 4 + 2] = u.v2[2]; q2[j * 4 + 3] = u.v2[3];
    }
    float s[4];
#pragma unroll
    for (int g = 0; g < 4; ++g) {
      float a = 0.f;
#pragma unroll
      for (int j = 0; j < 4; ++j) {
        v8split u;
        u.v8 = *(const f16x8*)qvp(smem, t, 512 + g * 128 + db + j * 16);
        a = fdot2f(q2[j * 4 + 0], u.v2[0], a);
        a = fdot2f(q2[j * 4 + 1], u.v2[1], a);
        a = fdot2f(q2[j * 4 + 2], u.v2[2], a);
        a = fdot2f(q2[j * 4 + 3], u.v2[3], a);
      }
      s[g] = a;
    }
    // merge the two d-halves (lane ^ 1), both lanes end with the full dot
#pragma unroll
    for (int g = 0; g < 4; ++g) s[g] += qswapf(s[g]);

    float mx = -1e30f;
#pragma unroll
    for (int g = 0; g < 4; ++g) {
      float v = fminf(fmaxf(s[g] * 0.125f, -10.f), 10.f);  // clip BEFORE softmax
      s[g] = v; mx = fmaxf(mx, v);
    }
    float sum = 0.f;
#pragma unroll
    for (int g = 0; g < 4; ++g) { s[g] = __expf(s[g] - mx); sum += s[g]; }
    float inv = 1.f / sum;
#pragma unroll
    for (int g = 0; g < 4; ++g) s[g] *= inv;

    // O[t][h][d-half] in fp32 (32 values), V streamed g-wise (broadcast reads)
    float o[32] = {};
#pragma unroll
    for (int g = 0; g < 4; ++g) {
      float p = s[g];
#pragma unroll
      for (int j = 0; j < 4; ++j) {
        v8split u;
        u.v8 = *(const f16x8*)qvp(smem, t, 1024 + g * 128 + db + j * 16);
#pragma unroll
        for (int i = 0; i < 4; ++i) {
          o[j * 8 + 2 * i]     += p * (float)u.v2[i][0];
          o[j * 8 + 2 * i + 1] += p * (float)u.v2[i][1];
        }
      }
    }
    // out2 row = h*16 + t/4, colbyte = (t&3)*128 + dh*64 + j*16. Reuse bufX.
    const int row = h * 16 + (t >> 2);
    const int cb0 = (t & 3) * 128 + db;
#pragma unroll
    for (int j = 0; j < 4; ++j) {
      f16x8 ov;
      ov[0] = (f16)o[j * 8 + 0]; ov[1] = (f16)o[j * 8 + 1];
      ov[2] = (f16)o[j * 8 + 2]; ov[3] = (f16)o[j * 8 + 3];
      ov[4] = (f16)o[j * 8 + 4]; ov[5] = (f16)o[j * 8 + 5];
      ov[6] = (f16)o[j * 8 + 6]; ov[7] = (f16)o[j * 8 + 7];
      *(f16x8*)xwp(bufX, row, cb0 + j * 16) = ov;
    }
  }
  __syncthreads();  // bar2: out2 visible; prefetch drained

  // GEMM2: final[64 x 256] = out2 @ w_proj^T; D col=c3 -> o2T[c3][t].
  {
    f32x4 acc2[4][2] = {};
#pragma unroll
    for (int kt = 0; kt < 8; ++kt) {
      f16x8 afr[4];
#pragma unroll
      for (int mt = 0; mt < 4; ++mt)
        afr[mt] = *(const f16x8*)xwp(bufX, mt * 16 + lcol, kt * 64 + lq * 16);
#pragma unroll
      for (int nt = 0; nt < 2; ++nt) {
        f16x8 bfr = *(const f16x8*)(wp_h + (wv * 32 + nt * 16 + lcol) * 256 + kt * 32 + lq * 8);
#pragma unroll
        for (int mt = 0; mt < 4; ++mt)
          acc2[mt][nt] = __builtin_amdgcn_mfma_f32_16x16x32_f16(afr[mt], bfr, acc2[mt][nt], 0, 0, 0);
      }
    }
    f16* ob = o2T + (size_t)wi * 16384;
#pragma unroll
    for (int mt = 0; mt < 4; ++mt)
#pragma unroll
      for (int nt = 0; nt < 2; ++nt) {
        int c3 = wv * 32 + nt * 16 + lcol;
        f16x4 hv;
        hv[0] = (f16)acc2[mt][nt][0]; hv[1] = (f16)acc2[mt][nt][1];
        hv[2] = (f16)acc2[mt][nt][2]; hv[3] = (f16)acc2[mt][nt][3];
        *(f16x4*)(ob + c3 * 64 + mt * 16 + lq * 4) = hv;
      }
  }
  // no trailing barrier: next GEMM1 touches qkv (safe after bar2) and bufY.
}

// ---- K2: persistent block = 8 windows, double-buffered xw prefetch ----
// amdgpu_waves_per_eu(2,2): occupancy is LDS-bound at 1 block/CU = 2
// waves/EU; cap the allocator's occupancy target there so it may use up to
// 256 VGPRs instead of spilling at the default 4-wave/128-VGPR target.
__global__ __launch_bounds__(512)
__attribute__((amdgpu_waves_per_eu(2, 2))) void win_attn_k(
    const f16* __restrict__ xw_all, const f16* __restrict__ wq_h,
    const f16* __restrict__ wp_h, f16* __restrict__ o2T) {
  extern __shared__ char smem[];
  const int tid = threadIdx.x, wv = tid >> 6, lane = tid & 63;
  const int lcol = lane & 15, lq = lane >> 4;
  const int base = blockIdx.x * 8;
  char* buf0 = smem;
  char* buf1 = smem + 32768;
  {
    const char* g = (const char*)(xw_all + (size_t)base * 16384) + wv * 4096 + lane * 16;
#pragma unroll
    for (int i = 0; i < 4; ++i)
      __builtin_amdgcn_global_load_lds(
          (const __attribute__((address_space(1))) void*)(g + i * 1024),
          (__attribute__((address_space(3))) void*)(buf0 + wv * 4096 + i * 1024), 16, 0, 0);
  }
  __syncthreads();
#pragma unroll 1
  for (int jj = 0; jj < 4; ++jj) {
    win_body(smem, buf0, buf1, xw_all, wq_h, wp_h, o2T, base + 2 * jj, true, wv, lane, lcol, lq);
    win_body(smem, buf1, buf0, xw_all, wq_h, wp_h, o2T, base + 2 * jj + 1, jj != 3, wv, lane, lcol, lq);
  }
}

extern "C" void kernel_launch(void* const* d_in, const int* in_sizes, int n_in,
                              void* d_out, int out_size, void* d_ws, size_t ws_size,
                              hipStream_t stream) {
  const float* x = (const float*)d_in[0];
  const float* wq = (const float*)d_in[1];
  const float* wp = (const float*)d_in[2];
  float* out = (float*)d_out;
  char* ws = (char*)d_ws;
  f16* wq_h = (f16*)(ws + WQH_OFF);
  f16* wp_h = (f16*)(ws + WPH_OFF);
  f16* xw_all = (f16*)(ws + XW_OFF);
  f16* o2T = (f16*)(ws + O2_OFF);

  (void)hipFuncSetAttribute((const void*)win_attn_k,
                            hipFuncAttributeMaxDynamicSharedMemorySize, SMEM_TOTAL);

  cvt_weights_k<<<1024, 256, 0, stream>>>(wq, wp, wq_h, wp_h);
  gather_k<<<4096, 256, 0, stream>>>(x, xw_all);
  win_attn_k<<<256, 512, SMEM_TOTAL, stream>>>(xw_all, wq_h, wp_h, o2T);
  scatter_k<<<4096, 256, 0, stream>>>(o2T, out);
}